// Round 2
// baseline (301.215 us; speedup 1.0000x reference)
//
#include <hip/hip_runtime.h>

typedef unsigned short u16;
typedef unsigned int u32;
typedef __attribute__((ext_vector_type(8))) short bf16x8;
typedef __attribute__((ext_vector_type(4))) float f32x4;

#define NPTS 2048
#define CFEAT 256
#define NS 32
#define MTOT 262144           // 4*2048*32
#define NBLK 4096             // MTOT/64 m-tiles
#define INV_N (1.0f/262144.0f)

__device__ __forceinline__ float bf2f(u16 u) {
    union { u32 i; float f; } v; v.i = ((u32)u) << 16; return v.f;
}
__device__ __forceinline__ u16 f2bf(float f) {
    union { float f; u32 i; } v; v.f = f;
    u32 i = v.i;
    return (u16)((i + 0x7fffu + ((i >> 16) & 1u)) >> 16);
}

// ---------------- prep: pack W1 -> [feat(256) | xyz(3) | 0(29)] (K=288), W2 (K=256), bf16 ----------------
__global__ __launch_bounds__(256) void prep_k(const float* __restrict__ W1, const float* __restrict__ W2,
                                              u16* __restrict__ Wp1, u16* __restrict__ Wp2) {
    int o = blockIdx.x, t = threadIdx.x;
    Wp1[o * 288 + t] = f2bf(W1[o * 259 + 3 + t]);
    if (t < 32) Wp1[o * 288 + 256 + t] = (t < 3) ? f2bf(W1[o * 259 + t]) : (u16)0;
    Wp2[o * 256 + t] = f2bf(W2[o * 256 + t]);
}

// ---------------- cylinder query: wave per point, ballot compaction ----------------
__global__ __launch_bounds__(256) void query_k(const float* __restrict__ xyz, const float* __restrict__ rot,
                                               int* __restrict__ idx) {
    int pid = blockIdx.x * 4 + (threadIdx.x >> 6);
    int lane = threadIdx.x & 63;
    int b = pid >> 11, p = pid & 2047;
    const float* xb = xyz + (size_t)b * NPTS * 3;
    float px = xb[p * 3 + 0], py = xb[p * 3 + 1], pz = xb[p * 3 + 2];
    const float* rp = rot + (size_t)pid * 9;
    float r00 = rp[0], r01 = rp[1], r02 = rp[2];
    float r10 = rp[3], r11 = rp[4], r12 = rp[5];
    float r20 = rp[6], r21 = rp[7], r22 = rp[8];
    int cnt = 0, first = 0;
    for (int n0 = 0; n0 < NPTS && cnt < NS; n0 += 64) {
        int n = n0 + lane;
        // exact fp32, sequential order, no fma contraction -> match numpy mask bitwise
        float dx = __fsub_rn(xb[n * 3 + 0], px);
        float dy = __fsub_rn(xb[n * 3 + 1], py);
        float dz = __fsub_rn(xb[n * 3 + 2], pz);
        float a0 = __fadd_rn(__fadd_rn(__fmul_rn(r00, dx), __fmul_rn(r01, dy)), __fmul_rn(r02, dz));
        float a1 = __fadd_rn(__fadd_rn(__fmul_rn(r10, dx), __fmul_rn(r11, dy)), __fmul_rn(r12, dz));
        float a2 = __fadd_rn(__fadd_rn(__fmul_rn(r20, dx), __fmul_rn(r21, dy)), __fmul_rn(r22, dz));
        float t2 = __fadd_rn(__fmul_rn(a1, a1), __fmul_rn(a2, a2));
        bool valid = (t2 < 0.0025f) && (a0 > -0.02f) && (a0 < 0.04f);
        unsigned long long bal = __ballot(valid);
        if (cnt == 0 && bal) first = n0 + __builtin_ctzll(bal);
        int rank = __builtin_popcountll(bal & ((1ull << lane) - 1ull));
        int slot = cnt + rank;
        if (valid && slot < NS) idx[(size_t)pid * NS + slot] = n;
        cnt += __builtin_popcountll(bal);
    }
    int filled = cnt < NS ? cnt : NS;
    if (lane >= filled && lane < NS) idx[(size_t)pid * NS + lane] = (cnt > 0) ? first : 0;
}

// ---------------- features (B,C,N) fp32 -> featT (B,N,C) bf16 ----------------
__global__ __launch_bounds__(256) void featT_k(const float* __restrict__ feat, u16* __restrict__ featT) {
    __shared__ float sm[32 * 33];
    int b = blockIdx.z;
    int n0 = blockIdx.x * 32, c0 = blockIdx.y * 32;
    int t = threadIdx.x, x = t & 31, y = t >> 5;
    #pragma unroll
    for (int rr = 0; rr < 4; rr++) {
        int c = c0 + y + rr * 8;
        sm[(y + rr * 8) * 33 + x] = feat[((size_t)(b * CFEAT + c)) * NPTS + n0 + x];
    }
    __syncthreads();
    #pragma unroll
    for (int rr = 0; rr < 4; rr++) {
        int n = n0 + y + rr * 8;
        featT[((size_t)(b * NPTS + n)) * CFEAT + c0 + x] = f2bf(sm[x * 33 + (y + rr * 8)]);
    }
}

// ---------------- gxyz: rotated, scaled neighbor offsets, (MTOT,4) bf16 ----------------
__global__ __launch_bounds__(256) void gxyz_k(const float* __restrict__ xyz, const float* __restrict__ rot,
                                              const int* __restrict__ idx, u16* __restrict__ gxyz) {
    int m = blockIdx.x * 256 + threadIdx.x;
    int pid = m >> 5;
    int b = pid >> 11, p = pid & 2047;
    int i = idx[m];
    const float* xb = xyz + (size_t)b * NPTS * 3;
    float dx = (xb[i * 3 + 0] - xb[p * 3 + 0]) * 20.0f;
    float dy = (xb[i * 3 + 1] - xb[p * 3 + 1]) * 20.0f;
    float dz = (xb[i * 3 + 2] - xb[p * 3 + 2]) * 20.0f;
    const float* rp = rot + (size_t)pid * 9;
    float g0 = dx * rp[0] + dy * rp[3] + dz * rp[6];   // row-vector times rot (einsum bpsj,bpjk)
    float g1 = dx * rp[1] + dy * rp[4] + dz * rp[7];
    float g2 = dx * rp[2] + dy * rp[5] + dz * rp[8];
    uint2 v;
    v.x = (u32)f2bf(g0) | ((u32)f2bf(g1) << 16);
    v.y = (u32)f2bf(g2);
    *(uint2*)(gxyz + (size_t)m * 4) = v;
}

// ---------------- fused GEMM1 (+optional norm1+GEMM2) over one 64-row m-tile ----------------
// FULL=0: stats1 partials only.  FULL=1: norm1+relu -> LDS -> GEMM2 -> stats2 partials + y2 max/min per pid.
template <int FULL>
__global__ __launch_bounds__(256) void fused_k(
    const u16* __restrict__ featT, const u16* __restrict__ gxyz, const int* __restrict__ idx,
    const u16* __restrict__ Wp1, const u16* __restrict__ Wp2, const float* __restrict__ ab1,
    float* __restrict__ psum, float* __restrict__ psq,
    float* __restrict__ ymax, float* __restrict__ ymin)
{
    __shared__ __attribute__((aligned(16))) u16 As[64 * 32];     // 4 KB
    __shared__ __attribute__((aligned(16))) u16 Bs[256 * 32];    // 16 KB
    __shared__ __attribute__((aligned(16))) u16 y1s[FULL ? 64 * 264 : 16]; // 33 KB (pad +8 breaks 16-way banks)
    __shared__ int rowbase_s[64];

    const int tid = threadIdx.x;
    const int lane = tid & 63, wave = tid >> 6;
    const int quad = lane >> 4, tl = lane & 15;
    const int bx = blockIdx.x;
    const int m0 = bx * 64;

    if (tid < 64) {
        int m = m0 + tid;
        int gi = idx[m];
        int b = m >> 16;                         // b = (m/32)/2048
        rowbase_s[tid] = (b * NPTS + gi) * CFEAT;
    }
    __syncthreads();
    const int srow = tid >> 2, sc16 = tid & 3;   // staging: row 0..63, 8-col chunk 0..3
    const int abase = rowbase_s[srow] + sc16 * 8;

    f32x4 acc[4][4];
    #pragma unroll
    for (int i = 0; i < 4; i++)
        #pragma unroll
        for (int j = 0; j < 4; j++) acc[i][j] = (f32x4){0.f, 0.f, 0.f, 0.f};

    auto mfma_tile = [&](f32x4 (&ac)[4][4], const u16* a_lds, int a_stride) {
        bf16x8 af[4], bv[4];
        #pragma unroll
        for (int i = 0; i < 4; i++) af[i] = *(const bf16x8*)(a_lds + (i * 16 + tl) * a_stride + quad * 8);
        #pragma unroll
        for (int j = 0; j < 4; j++) bv[j] = *(const bf16x8*)(Bs + (wave * 64 + j * 16 + tl) * 32 + quad * 8);
        #pragma unroll
        for (int i = 0; i < 4; i++)
            #pragma unroll
            for (int j = 0; j < 4; j++)
                ac[i][j] = __builtin_amdgcn_mfma_f32_16x16x32_bf16(af[i], bv[j], ac[i][j], 0, 0, 0);
    };

    // ---- GEMM1: K = 256 feat (gathered) + 1 xyz tile ----
    for (int ks = 0; ks < 8; ks++) {
        const int k0 = ks * 32;
        __syncthreads();
        *(uint4*)(As + srow * 32 + sc16 * 8) = *(const uint4*)(featT + abase + k0);
        #pragma unroll
        for (int q = 0; q < 4; q++) {
            int o = srow + q * 64;
            *(uint4*)(Bs + o * 32 + sc16 * 8) = *(const uint4*)(Wp1 + o * 288 + k0 + sc16 * 8);
        }
        __syncthreads();
        mfma_tile(acc, As, 32);
    }
    {   // xyz K-tile (cols 256..287 of Wp1; A cols = [gx,gy,gz,0...])
        __syncthreads();
        uint4 va = make_uint4(0, 0, 0, 0);
        if (sc16 == 0) {
            uint2 g2 = *(const uint2*)(gxyz + (size_t)(m0 + srow) * 4);
            va.x = g2.x; va.y = g2.y;
        }
        *(uint4*)(As + srow * 32 + sc16 * 8) = va;
        #pragma unroll
        for (int q = 0; q < 4; q++) {
            int o = srow + q * 64;
            *(uint4*)(Bs + o * 32 + sc16 * 8) = *(const uint4*)(Wp1 + o * 288 + 256 + sc16 * 8);
        }
        __syncthreads();
        mfma_tile(acc, As, 32);
    }

    if (!FULL) {
        #pragma unroll
        for (int j = 0; j < 4; j++) {
            float s = 0.f, q2 = 0.f;
            #pragma unroll
            for (int i = 0; i < 4; i++)
                #pragma unroll
                for (int r = 0; r < 4; r++) { float v = acc[i][j][r]; s += v; q2 += v * v; }
            s += __shfl_xor(s, 16); s += __shfl_xor(s, 32);
            q2 += __shfl_xor(q2, 16); q2 += __shfl_xor(q2, 32);
            if (quad == 0) {
                int col = wave * 64 + j * 16 + tl;
                psum[(size_t)col * NBLK + bx] = s;
                psq[(size_t)col * NBLK + bx] = q2;
            }
        }
        return;
    }

    // ---- norm1 + relu -> y1s (bf16) ----
    #pragma unroll
    for (int j = 0; j < 4; j++) {
        int col = wave * 64 + j * 16 + tl;
        float a = ab1[col], bb = ab1[256 + col];
        #pragma unroll
        for (int i = 0; i < 4; i++)
            #pragma unroll
            for (int r = 0; r < 4; r++) {
                float v = fmaxf(fmaf(acc[i][j][r], a, bb), 0.f);
                y1s[(i * 16 + quad * 4 + r) * 264 + col] = f2bf(v);
            }
    }

    // ---- GEMM2: y2(64x256) = y1s(64x256) x W2^T ----
    f32x4 acc2[4][4];
    #pragma unroll
    for (int i = 0; i < 4; i++)
        #pragma unroll
        for (int j = 0; j < 4; j++) acc2[i][j] = (f32x4){0.f, 0.f, 0.f, 0.f};
    for (int ks = 0; ks < 8; ks++) {
        const int k0 = ks * 32;
        __syncthreads();   // also covers y1s-write -> read on first iter
        #pragma unroll
        for (int q = 0; q < 4; q++) {
            int o = srow + q * 64;
            *(uint4*)(Bs + o * 32 + sc16 * 8) = *(const uint4*)(Wp2 + o * 256 + k0 + sc16 * 8);
        }
        __syncthreads();
        mfma_tile(acc2, y1s + k0, 264);
    }

    // ---- epilogue2: stats partials + per-pid max/min over s (rows i<2 -> pid0, i>=2 -> pid1) ----
    #pragma unroll
    for (int j = 0; j < 4; j++) {
        int col = wave * 64 + j * 16 + tl;
        float s = 0.f, q2 = 0.f;
        float mx0 = -3.0e38f, mn0 = 3.0e38f, mx1 = -3.0e38f, mn1 = 3.0e38f;
        #pragma unroll
        for (int i = 0; i < 4; i++)
            #pragma unroll
            for (int r = 0; r < 4; r++) {
                float v = acc2[i][j][r];
                s += v; q2 += v * v;
                if (i < 2) { mx0 = fmaxf(mx0, v); mn0 = fminf(mn0, v); }
                else       { mx1 = fmaxf(mx1, v); mn1 = fminf(mn1, v); }
            }
        s += __shfl_xor(s, 16); s += __shfl_xor(s, 32);
        q2 += __shfl_xor(q2, 16); q2 += __shfl_xor(q2, 32);
        mx0 = fmaxf(mx0, __shfl_xor(mx0, 16)); mx0 = fmaxf(mx0, __shfl_xor(mx0, 32));
        mn0 = fminf(mn0, __shfl_xor(mn0, 16)); mn0 = fminf(mn0, __shfl_xor(mn0, 32));
        mx1 = fmaxf(mx1, __shfl_xor(mx1, 16)); mx1 = fmaxf(mx1, __shfl_xor(mx1, 32));
        mn1 = fminf(mn1, __shfl_xor(mn1, 16)); mn1 = fminf(mn1, __shfl_xor(mn1, 32));
        if (quad == 0) {
            psum[(size_t)col * NBLK + bx] = s;
            psq[(size_t)col * NBLK + bx] = q2;
            size_t p0 = (size_t)(bx * 2) * 256 + col;
            size_t p1 = (size_t)(bx * 2 + 1) * 256 + col;
            ymax[p0] = mx0; ymin[p0] = mn0;
            ymax[p1] = mx1; ymin[p1] = mn1;
        }
    }
}

// ---------------- reduce partials -> per-channel (a,b) affine ----------------
__global__ __launch_bounds__(256) void reduce_k(const float* __restrict__ psum, const float* __restrict__ psq,
                                                const float* __restrict__ gamma, const float* __restrict__ beta,
                                                float* __restrict__ ab) {
    __shared__ float red[8];
    int c = blockIdx.x, t = threadIdx.x;
    float s = 0.f, q = 0.f;
    for (int k = t; k < NBLK; k += 256) { s += psum[(size_t)c * NBLK + k]; q += psq[(size_t)c * NBLK + k]; }
    #pragma unroll
    for (int o = 32; o >= 1; o >>= 1) { s += __shfl_xor(s, o); q += __shfl_xor(q, o); }
    int lane = t & 63, w = t >> 6;
    if (lane == 0) { red[w] = s; red[4 + w] = q; }
    __syncthreads();
    if (t == 0) {
        float S = red[0] + red[1] + red[2] + red[3];
        float Q = red[4] + red[5] + red[6] + red[7];
        float mu = S * INV_N;
        float var = Q * INV_N - mu * mu;
        float a = gamma[c] * rsqrtf(var + 1e-5f);
        ab[c] = a;
        ab[256 + c] = beta[c] - mu * a;
    }
}

// ---------------- final: relu(a*(a>=0?max:min)+b), transpose (pid,O) -> (B,O,N) ----------------
__global__ __launch_bounds__(256) void final_k(const float* __restrict__ ymax, const float* __restrict__ ymin,
                                               const float* __restrict__ ab, float* __restrict__ out) {
    __shared__ float sm[32 * 33];
    int b = blockIdx.z;
    int n0 = blockIdx.x * 32, o0 = blockIdx.y * 32;
    int t = threadIdx.x, x = t & 31, y = t >> 5;
    #pragma unroll
    for (int rr = 0; rr < 4; rr++) {
        int n = n0 + y + rr * 8;
        int o = o0 + x;
        float a = ab[o], bb = ab[256 + o];
        size_t p = (size_t)(b * NPTS + n) * 256 + o;
        float v = (a >= 0.f) ? ymax[p] : ymin[p];
        sm[(y + rr * 8) * 33 + x] = fmaxf(fmaf(v, a, bb), 0.f);
    }
    __syncthreads();
    #pragma unroll
    for (int rr = 0; rr < 4; rr++)
        out[((size_t)(b * 256 + o0 + y + rr * 8)) * NPTS + n0 + x] = sm[x * 33 + (y + rr * 8)];
}

extern "C" void kernel_launch(void* const* d_in, const int* in_sizes, int n_in,
                              void* d_out, int out_size, void* d_ws, size_t ws_size,
                              hipStream_t stream) {
    const float* xyz    = (const float*)d_in[0];
    const float* feat   = (const float*)d_in[1];
    const float* rot    = (const float*)d_in[2];
    const float* W1     = (const float*)d_in[3];
    const float* gamma1 = (const float*)d_in[4];
    const float* beta1  = (const float*)d_in[5];
    const float* W2     = (const float*)d_in[6];
    const float* gamma2 = (const float*)d_in[7];
    const float* beta2  = (const float*)d_in[8];
    float* out = (float*)d_out;

    // workspace: 32,788,480 bytes total
    char* ws = (char*)d_ws;
    u16*   featT = (u16*)(ws + 0);           //  4,194,304
    int*   idx   = (int*)(ws + 4194304);     //  1,048,576
    u16*   gxyz  = (u16*)(ws + 5242880);     //  2,097,152
    u16*   Wp1   = (u16*)(ws + 7340032);     //    147,456
    u16*   Wp2   = (u16*)(ws + 7487488);     //    131,072
    float* ab1   = (float*)(ws + 7618560);   //      2,048
    float* ab2   = (float*)(ws + 7620608);   //      2,048
    float* psum  = (float*)(ws + 7622656);   //  4,194,304
    float* psq   = (float*)(ws + 11816960);  //  4,194,304
    float* ymax  = (float*)(ws + 16011264);  //  8,388,608
    float* ymin  = (float*)(ws + 24399872);  //  8,388,608

    prep_k<<<256, 256, 0, stream>>>(W1, W2, Wp1, Wp2);
    query_k<<<2048, 256, 0, stream>>>(xyz, rot, idx);
    featT_k<<<dim3(64, 8, 4), 256, 0, stream>>>(feat, featT);
    gxyz_k<<<1024, 256, 0, stream>>>(xyz, rot, idx, gxyz);
    fused_k<0><<<NBLK, 256, 0, stream>>>(featT, gxyz, idx, Wp1, Wp2, ab1, psum, psq, ymax, ymin);
    reduce_k<<<256, 256, 0, stream>>>(psum, psq, gamma1, beta1, ab1);
    fused_k<1><<<NBLK, 256, 0, stream>>>(featT, gxyz, idx, Wp1, Wp2, ab1, psum, psq, ymax, ymin);
    reduce_k<<<256, 256, 0, stream>>>(psum, psq, gamma2, beta2, ab2);
    final_k<<<dim3(64, 8, 4), 256, 0, stream>>>(ymax, ymin, ab2, out);
}

// Round 3
// 255.336 us; speedup vs baseline: 1.1797x; 1.1797x over previous
//
#include <hip/hip_runtime.h>

typedef unsigned short u16;
typedef unsigned int u32;
typedef __attribute__((ext_vector_type(8))) short bf16x8;
typedef __attribute__((ext_vector_type(4))) float f32x4;

#define NPTS 2048
#define CFEAT 256
#define NS 32
#define MTOT 262144           // 4*2048*32
#define NBLK 4096             // MTOT/64 m-tiles
#define INV_N (1.0f/262144.0f)

__device__ __forceinline__ float bf2f(u16 u) {
    union { u32 i; float f; } v; v.i = ((u32)u) << 16; return v.f;
}
__device__ __forceinline__ u16 f2bf(float f) {
    union { float f; u32 i; } v; v.f = f;
    u32 i = v.i;
    return (u16)((i + 0x7fffu + ((i >> 16) & 1u)) >> 16);
}

// ---------------- prep: pack W1 -> [feat(256) | xyz(3) | 0(29)] (K=288), W2 (K=256), bf16 ----------------
__global__ __launch_bounds__(256) void prep_k(const float* __restrict__ W1, const float* __restrict__ W2,
                                              u16* __restrict__ Wp1, u16* __restrict__ Wp2) {
    int o = blockIdx.x, t = threadIdx.x;
    Wp1[o * 288 + t] = f2bf(W1[o * 259 + 3 + t]);
    if (t < 32) Wp1[o * 288 + 256 + t] = (t < 3) ? f2bf(W1[o * 259 + t]) : (u16)0;
    Wp2[o * 256 + t] = f2bf(W2[o * 256 + t]);
}

// ---------------- cylinder query: wave per point, ballot compaction ----------------
__global__ __launch_bounds__(256) void query_k(const float* __restrict__ xyz, const float* __restrict__ rot,
                                               int* __restrict__ idx) {
    int pid = blockIdx.x * 4 + (threadIdx.x >> 6);
    int lane = threadIdx.x & 63;
    int b = pid >> 11, p = pid & 2047;
    const float* xb = xyz + (size_t)b * NPTS * 3;
    float px = xb[p * 3 + 0], py = xb[p * 3 + 1], pz = xb[p * 3 + 2];
    const float* rp = rot + (size_t)pid * 9;
    float r00 = rp[0], r01 = rp[1], r02 = rp[2];
    float r10 = rp[3], r11 = rp[4], r12 = rp[5];
    float r20 = rp[6], r21 = rp[7], r22 = rp[8];
    int cnt = 0, first = 0;
    for (int n0 = 0; n0 < NPTS && cnt < NS; n0 += 64) {
        int n = n0 + lane;
        // exact fp32, sequential order, no fma contraction -> match numpy mask bitwise
        float dx = __fsub_rn(xb[n * 3 + 0], px);
        float dy = __fsub_rn(xb[n * 3 + 1], py);
        float dz = __fsub_rn(xb[n * 3 + 2], pz);
        float a0 = __fadd_rn(__fadd_rn(__fmul_rn(r00, dx), __fmul_rn(r01, dy)), __fmul_rn(r02, dz));
        float a1 = __fadd_rn(__fadd_rn(__fmul_rn(r10, dx), __fmul_rn(r11, dy)), __fmul_rn(r12, dz));
        float a2 = __fadd_rn(__fadd_rn(__fmul_rn(r20, dx), __fmul_rn(r21, dy)), __fmul_rn(r22, dz));
        float t2 = __fadd_rn(__fmul_rn(a1, a1), __fmul_rn(a2, a2));
        bool valid = (t2 < 0.0025f) && (a0 > -0.02f) && (a0 < 0.04f);
        unsigned long long bal = __ballot(valid);
        if (cnt == 0 && bal) first = n0 + __builtin_ctzll(bal);
        int rank = __builtin_popcountll(bal & ((1ull << lane) - 1ull));
        int slot = cnt + rank;
        if (valid && slot < NS) idx[(size_t)pid * NS + slot] = n;
        cnt += __builtin_popcountll(bal);
    }
    int filled = cnt < NS ? cnt : NS;
    if (lane >= filled && lane < NS) idx[(size_t)pid * NS + lane] = (cnt > 0) ? first : 0;
}

// ---------------- features (B,C,N) fp32 -> featT (B,N,C) bf16 ----------------
__global__ __launch_bounds__(256) void featT_k(const float* __restrict__ feat, u16* __restrict__ featT) {
    __shared__ float sm[32 * 33];
    int b = blockIdx.z;
    int n0 = blockIdx.x * 32, c0 = blockIdx.y * 32;
    int t = threadIdx.x, x = t & 31, y = t >> 5;
    #pragma unroll
    for (int rr = 0; rr < 4; rr++) {
        int c = c0 + y + rr * 8;
        sm[(y + rr * 8) * 33 + x] = feat[((size_t)(b * CFEAT + c)) * NPTS + n0 + x];
    }
    __syncthreads();
    #pragma unroll
    for (int rr = 0; rr < 4; rr++) {
        int n = n0 + y + rr * 8;
        featT[((size_t)(b * NPTS + n)) * CFEAT + c0 + x] = f2bf(sm[x * 33 + (y + rr * 8)]);
    }
}

// ---------------- gxyz: rotated, scaled neighbor offsets, (MTOT,4) bf16 ----------------
__global__ __launch_bounds__(256) void gxyz_k(const float* __restrict__ xyz, const float* __restrict__ rot,
                                              const int* __restrict__ idx, u16* __restrict__ gxyz) {
    int m = blockIdx.x * 256 + threadIdx.x;
    int pid = m >> 5;
    int b = pid >> 11, p = pid & 2047;
    int i = idx[m];
    const float* xb = xyz + (size_t)b * NPTS * 3;
    float dx = (xb[i * 3 + 0] - xb[p * 3 + 0]) * 20.0f;
    float dy = (xb[i * 3 + 1] - xb[p * 3 + 1]) * 20.0f;
    float dz = (xb[i * 3 + 2] - xb[p * 3 + 2]) * 20.0f;
    const float* rp = rot + (size_t)pid * 9;
    float g0 = dx * rp[0] + dy * rp[3] + dz * rp[6];
    float g1 = dx * rp[1] + dy * rp[4] + dz * rp[7];
    float g2 = dx * rp[2] + dy * rp[5] + dz * rp[8];
    uint2 v;
    v.x = (u32)f2bf(g0) | ((u32)f2bf(g1) << 16);
    v.y = (u32)f2bf(g2);
    *(uint2*)(gxyz + (size_t)m * 4) = v;
}

// ---------------- fused GEMM1 (+optional norm1+GEMM2) over one 64-row m-tile ----------------
// FULL=0: stats1 partials (+optional y1 fragment spill when STORE=1).
// FULL=1: recompute GEMM1, norm1+relu -> LDS -> GEMM2 -> stats2 + y2 max/min (fallback path).
template <int FULL, int STORE>
__global__ __launch_bounds__(256) void fused_k(
    const u16* __restrict__ featT, const u16* __restrict__ gxyz, const int* __restrict__ idx,
    const u16* __restrict__ Wp1, const u16* __restrict__ Wp2, const float* __restrict__ ab1,
    float* __restrict__ psum, float* __restrict__ psq,
    float* __restrict__ ymax, float* __restrict__ ymin, uint2* __restrict__ y1f)
{
    __shared__ __attribute__((aligned(16))) u16 As[64 * 32];     // 4 KB
    __shared__ __attribute__((aligned(16))) u16 Bs[256 * 32];    // 16 KB
    __shared__ __attribute__((aligned(16))) u16 y1s[FULL ? 64 * 264 : 16];
    __shared__ int rowbase_s[64];

    const int tid = threadIdx.x;
    const int lane = tid & 63, wave = tid >> 6;
    const int quad = lane >> 4, tl = lane & 15;
    const int bx = blockIdx.x;
    const int m0 = bx * 64;

    if (tid < 64) {
        int m = m0 + tid;
        int gi = idx[m];
        int b = m >> 16;
        rowbase_s[tid] = (b * NPTS + gi) * CFEAT;
    }
    __syncthreads();
    const int srow = tid >> 2, sc16 = tid & 3;
    const int abase = rowbase_s[srow] + sc16 * 8;

    f32x4 acc[4][4];
    #pragma unroll
    for (int i = 0; i < 4; i++)
        #pragma unroll
        for (int j = 0; j < 4; j++) acc[i][j] = (f32x4){0.f, 0.f, 0.f, 0.f};

    auto mfma_tile = [&](f32x4 (&ac)[4][4], const u16* a_lds, int a_stride) {
        bf16x8 af[4], bv[4];
        #pragma unroll
        for (int i = 0; i < 4; i++) af[i] = *(const bf16x8*)(a_lds + (i * 16 + tl) * a_stride + quad * 8);
        #pragma unroll
        for (int j = 0; j < 4; j++) bv[j] = *(const bf16x8*)(Bs + (wave * 64 + j * 16 + tl) * 32 + quad * 8);
        #pragma unroll
        for (int i = 0; i < 4; i++)
            #pragma unroll
            for (int j = 0; j < 4; j++)
                ac[i][j] = __builtin_amdgcn_mfma_f32_16x16x32_bf16(af[i], bv[j], ac[i][j], 0, 0, 0);
    };

    // ---- GEMM1: K = 256 feat (gathered) + 1 xyz tile ----
    for (int ks = 0; ks < 8; ks++) {
        const int k0 = ks * 32;
        __syncthreads();
        *(uint4*)(As + srow * 32 + sc16 * 8) = *(const uint4*)(featT + abase + k0);
        #pragma unroll
        for (int q = 0; q < 4; q++) {
            int o = srow + q * 64;
            *(uint4*)(Bs + o * 32 + sc16 * 8) = *(const uint4*)(Wp1 + o * 288 + k0 + sc16 * 8);
        }
        __syncthreads();
        mfma_tile(acc, As, 32);
    }
    {   // xyz K-tile
        __syncthreads();
        uint4 va = make_uint4(0, 0, 0, 0);
        if (sc16 == 0) {
            uint2 g2 = *(const uint2*)(gxyz + (size_t)(m0 + srow) * 4);
            va.x = g2.x; va.y = g2.y;
        }
        *(uint4*)(As + srow * 32 + sc16 * 8) = va;
        #pragma unroll
        for (int q = 0; q < 4; q++) {
            int o = srow + q * 64;
            *(uint4*)(Bs + o * 32 + sc16 * 8) = *(const uint4*)(Wp1 + o * 288 + 256 + sc16 * 8);
        }
        __syncthreads();
        mfma_tile(acc, As, 32);
    }

    if (!FULL) {
        #pragma unroll
        for (int j = 0; j < 4; j++) {
            float s = 0.f, q2 = 0.f;
            #pragma unroll
            for (int i = 0; i < 4; i++) {
                float v0 = acc[i][j][0], v1 = acc[i][j][1], v2 = acc[i][j][2], v3 = acc[i][j][3];
                if (STORE) {
                    u32 lo = (u32)f2bf(v0) | ((u32)f2bf(v1) << 16);
                    u32 hi = (u32)f2bf(v2) | ((u32)f2bf(v3) << 16);
                    y1f[((size_t)(bx * 4 + wave) * 16 + i * 4 + j) * 64 + lane] = make_uint2(lo, hi);
                    // stats on the rounded values for self-consistency with pass 2
                    v0 = bf2f((u16)(lo & 0xffff)); v1 = bf2f((u16)(lo >> 16));
                    v2 = bf2f((u16)(hi & 0xffff)); v3 = bf2f((u16)(hi >> 16));
                }
                s += v0 + v1 + v2 + v3;
                q2 += v0 * v0 + v1 * v1 + v2 * v2 + v3 * v3;
            }
            s += __shfl_xor(s, 16); s += __shfl_xor(s, 32);
            q2 += __shfl_xor(q2, 16); q2 += __shfl_xor(q2, 32);
            if (quad == 0) {
                int col = wave * 64 + j * 16 + tl;
                psum[(size_t)col * NBLK + bx] = s;
                psq[(size_t)col * NBLK + bx] = q2;
            }
        }
        return;
    }

    // ---- norm1 + relu -> y1s (bf16) ----
    #pragma unroll
    for (int j = 0; j < 4; j++) {
        int col = wave * 64 + j * 16 + tl;
        float a = ab1[col], bb = ab1[256 + col];
        #pragma unroll
        for (int i = 0; i < 4; i++)
            #pragma unroll
            for (int r = 0; r < 4; r++) {
                float v = fmaxf(fmaf(acc[i][j][r], a, bb), 0.f);
                y1s[(i * 16 + quad * 4 + r) * 264 + col] = f2bf(v);
            }
    }

    // ---- GEMM2 ----
    f32x4 acc2[4][4];
    #pragma unroll
    for (int i = 0; i < 4; i++)
        #pragma unroll
        for (int j = 0; j < 4; j++) acc2[i][j] = (f32x4){0.f, 0.f, 0.f, 0.f};
    for (int ks = 0; ks < 8; ks++) {
        const int k0 = ks * 32;
        __syncthreads();
        #pragma unroll
        for (int q = 0; q < 4; q++) {
            int o = srow + q * 64;
            *(uint4*)(Bs + o * 32 + sc16 * 8) = *(const uint4*)(Wp2 + o * 256 + k0 + sc16 * 8);
        }
        __syncthreads();
        mfma_tile(acc2, y1s + k0, 264);
    }

    // ---- epilogue2 ----
    #pragma unroll
    for (int j = 0; j < 4; j++) {
        int col = wave * 64 + j * 16 + tl;
        float s = 0.f, q2 = 0.f;
        float mx0 = -3.0e38f, mn0 = 3.0e38f, mx1 = -3.0e38f, mn1 = 3.0e38f;
        #pragma unroll
        for (int i = 0; i < 4; i++)
            #pragma unroll
            for (int r = 0; r < 4; r++) {
                float v = acc2[i][j][r];
                s += v; q2 += v * v;
                if (i < 2) { mx0 = fmaxf(mx0, v); mn0 = fminf(mn0, v); }
                else       { mx1 = fmaxf(mx1, v); mn1 = fminf(mn1, v); }
            }
        s += __shfl_xor(s, 16); s += __shfl_xor(s, 32);
        q2 += __shfl_xor(q2, 16); q2 += __shfl_xor(q2, 32);
        mx0 = fmaxf(mx0, __shfl_xor(mx0, 16)); mx0 = fmaxf(mx0, __shfl_xor(mx0, 32));
        mn0 = fminf(mn0, __shfl_xor(mn0, 16)); mn0 = fminf(mn0, __shfl_xor(mn0, 32));
        mx1 = fmaxf(mx1, __shfl_xor(mx1, 16)); mx1 = fmaxf(mx1, __shfl_xor(mx1, 32));
        mn1 = fminf(mn1, __shfl_xor(mn1, 16)); mn1 = fminf(mn1, __shfl_xor(mn1, 32));
        if (quad == 0) {
            psum[(size_t)col * NBLK + bx] = s;
            psq[(size_t)col * NBLK + bx] = q2;
            size_t p0 = (size_t)(bx * 2) * 256 + col;
            size_t p1 = (size_t)(bx * 2 + 1) * 256 + col;
            ymax[p0] = mx0; ymin[p0] = mn0;
            ymax[p1] = mx1; ymin[p1] = mn1;
        }
    }
}

// ---------------- pass 2 (big-ws path): reload y1 frags, norm+relu -> LDS -> GEMM2 ----------------
__global__ __launch_bounds__(256) void fused2_k(
    const uint2* __restrict__ y1f, const u16* __restrict__ Wp2, const float* __restrict__ ab1,
    float* __restrict__ psum, float* __restrict__ psq,
    float* __restrict__ ymax, float* __restrict__ ymin)
{
    __shared__ __attribute__((aligned(16))) u16 Bs[256 * 32];    // 16 KB
    __shared__ __attribute__((aligned(16))) u16 y1s[64 * 264];   // 33.8 KB -> 3 blocks/CU
    const int tid = threadIdx.x;
    const int lane = tid & 63, wave = tid >> 6;
    const int quad = lane >> 4, tl = lane & 15;
    const int bx = blockIdx.x;

    // reload this lane's own pass-1 fragments (coalesced), normalize, deposit to LDS
    #pragma unroll
    for (int j = 0; j < 4; j++) {
        int col = wave * 64 + j * 16 + tl;
        float a = ab1[col], bb = ab1[256 + col];
        #pragma unroll
        for (int i = 0; i < 4; i++) {
            uint2 v = y1f[((size_t)(bx * 4 + wave) * 16 + i * 4 + j) * 64 + lane];
            float f0 = bf2f((u16)(v.x & 0xffff)), f1 = bf2f((u16)(v.x >> 16));
            float f2 = bf2f((u16)(v.y & 0xffff)), f3 = bf2f((u16)(v.y >> 16));
            int rb = (i * 16 + quad * 4) * 264 + col;
            y1s[rb] = f2bf(fmaxf(fmaf(f0, a, bb), 0.f));
            y1s[rb + 264] = f2bf(fmaxf(fmaf(f1, a, bb), 0.f));
            y1s[rb + 528] = f2bf(fmaxf(fmaf(f2, a, bb), 0.f));
            y1s[rb + 792] = f2bf(fmaxf(fmaf(f3, a, bb), 0.f));
        }
    }

    const int srow = tid >> 2, sc16 = tid & 3;
    f32x4 acc2[4][4];
    #pragma unroll
    for (int i = 0; i < 4; i++)
        #pragma unroll
        for (int j = 0; j < 4; j++) acc2[i][j] = (f32x4){0.f, 0.f, 0.f, 0.f};

    for (int ks = 0; ks < 8; ks++) {
        const int k0 = ks * 32;
        __syncthreads();   // first iter: covers y1s writes
        #pragma unroll
        for (int q = 0; q < 4; q++) {
            int o = srow + q * 64;
            *(uint4*)(Bs + o * 32 + sc16 * 8) = *(const uint4*)(Wp2 + o * 256 + k0 + sc16 * 8);
        }
        __syncthreads();
        bf16x8 af[4], bv[4];
        #pragma unroll
        for (int i = 0; i < 4; i++) af[i] = *(const bf16x8*)(y1s + (i * 16 + tl) * 264 + k0 + quad * 8);
        #pragma unroll
        for (int j = 0; j < 4; j++) bv[j] = *(const bf16x8*)(Bs + (wave * 64 + j * 16 + tl) * 32 + quad * 8);
        #pragma unroll
        for (int i = 0; i < 4; i++)
            #pragma unroll
            for (int j = 0; j < 4; j++)
                acc2[i][j] = __builtin_amdgcn_mfma_f32_16x16x32_bf16(af[i], bv[j], acc2[i][j], 0, 0, 0);
    }

    #pragma unroll
    for (int j = 0; j < 4; j++) {
        int col = wave * 64 + j * 16 + tl;
        float s = 0.f, q2 = 0.f;
        float mx0 = -3.0e38f, mn0 = 3.0e38f, mx1 = -3.0e38f, mn1 = 3.0e38f;
        #pragma unroll
        for (int i = 0; i < 4; i++)
            #pragma unroll
            for (int r = 0; r < 4; r++) {
                float v = acc2[i][j][r];
                s += v; q2 += v * v;
                if (i < 2) { mx0 = fmaxf(mx0, v); mn0 = fminf(mn0, v); }
                else       { mx1 = fmaxf(mx1, v); mn1 = fminf(mn1, v); }
            }
        s += __shfl_xor(s, 16); s += __shfl_xor(s, 32);
        q2 += __shfl_xor(q2, 16); q2 += __shfl_xor(q2, 32);
        mx0 = fmaxf(mx0, __shfl_xor(mx0, 16)); mx0 = fmaxf(mx0, __shfl_xor(mx0, 32));
        mn0 = fminf(mn0, __shfl_xor(mn0, 16)); mn0 = fminf(mn0, __shfl_xor(mn0, 32));
        mx1 = fmaxf(mx1, __shfl_xor(mx1, 16)); mx1 = fmaxf(mx1, __shfl_xor(mx1, 32));
        mn1 = fminf(mn1, __shfl_xor(mn1, 16)); mn1 = fminf(mn1, __shfl_xor(mn1, 32));
        if (quad == 0) {
            psum[(size_t)col * NBLK + bx] = s;
            psq[(size_t)col * NBLK + bx] = q2;
            size_t p0 = (size_t)(bx * 2) * 256 + col;
            size_t p1 = (size_t)(bx * 2 + 1) * 256 + col;
            ymax[p0] = mx0; ymin[p0] = mn0;
            ymax[p1] = mx1; ymin[p1] = mn1;
        }
    }
}

// ---------------- reduce partials -> per-channel (a,b) affine ----------------
__global__ __launch_bounds__(256) void reduce_k(const float* __restrict__ psum, const float* __restrict__ psq,
                                                const float* __restrict__ gamma, const float* __restrict__ beta,
                                                float* __restrict__ ab) {
    __shared__ float red[8];
    int c = blockIdx.x, t = threadIdx.x;
    float s = 0.f, q = 0.f;
    for (int k = t; k < NBLK; k += 256) { s += psum[(size_t)c * NBLK + k]; q += psq[(size_t)c * NBLK + k]; }
    #pragma unroll
    for (int o = 32; o >= 1; o >>= 1) { s += __shfl_xor(s, o); q += __shfl_xor(q, o); }
    int lane = t & 63, w = t >> 6;
    if (lane == 0) { red[w] = s; red[4 + w] = q; }
    __syncthreads();
    if (t == 0) {
        float S = red[0] + red[1] + red[2] + red[3];
        float Q = red[4] + red[5] + red[6] + red[7];
        float mu = S * INV_N;
        float var = Q * INV_N - mu * mu;
        float a = gamma[c] * rsqrtf(var + 1e-5f);
        ab[c] = a;
        ab[256 + c] = beta[c] - mu * a;
    }
}

// ---------------- final: relu(a*(a>=0?max:min)+b), transpose -> (B,O,N) ----------------
__global__ __launch_bounds__(256) void final_k(const float* __restrict__ ymax, const float* __restrict__ ymin,
                                               const float* __restrict__ ab, float* __restrict__ out) {
    __shared__ float sm[32 * 33];
    int b = blockIdx.z;
    int n0 = blockIdx.x * 32, o0 = blockIdx.y * 32;
    int t = threadIdx.x, x = t & 31, y = t >> 5;
    #pragma unroll
    for (int rr = 0; rr < 4; rr++) {
        int n = n0 + y + rr * 8;
        int o = o0 + x;
        float a = ab[o], bb = ab[256 + o];
        size_t p = (size_t)(b * NPTS + n) * 256 + o;
        float v = (a >= 0.f) ? ymax[p] : ymin[p];
        sm[(y + rr * 8) * 33 + x] = fmaxf(fmaf(v, a, bb), 0.f);
    }
    __syncthreads();
    #pragma unroll
    for (int rr = 0; rr < 4; rr++)
        out[((size_t)(b * 256 + o0 + y + rr * 8)) * NPTS + n0 + x] = sm[x * 33 + (y + rr * 8)];
}

extern "C" void kernel_launch(void* const* d_in, const int* in_sizes, int n_in,
                              void* d_out, int out_size, void* d_ws, size_t ws_size,
                              hipStream_t stream) {
    const float* xyz    = (const float*)d_in[0];
    const float* feat   = (const float*)d_in[1];
    const float* rot    = (const float*)d_in[2];
    const float* W1     = (const float*)d_in[3];
    const float* gamma1 = (const float*)d_in[4];
    const float* beta1  = (const float*)d_in[5];
    const float* W2     = (const float*)d_in[6];
    const float* gamma2 = (const float*)d_in[7];
    const float* beta2  = (const float*)d_in[8];
    float* out = (float*)d_out;

    char* ws = (char*)d_ws;
    u16*   featT = (u16*)(ws + 0);           //  4,194,304
    int*   idx   = (int*)(ws + 4194304);     //  1,048,576
    u16*   gxyz  = (u16*)(ws + 5242880);     //  2,097,152
    u16*   Wp1   = (u16*)(ws + 7340032);     //    147,456
    u16*   Wp2   = (u16*)(ws + 7487488);     //    131,072
    float* ab1   = (float*)(ws + 7618560);   //      2,048
    float* ab2   = (float*)(ws + 7620608);   //      2,048
    float* psum  = (float*)(ws + 7622656);   //  4,194,304
    float* psq   = (float*)(ws + 11816960);  //  4,194,304
    float* ymax  = (float*)(ws + 16011264);  //  8,388,608
    float* ymin  = (float*)(ws + 24399872);  //  8,388,608
    uint2* y1f   = (uint2*)(ws + 32788480);  // 134,217,728 (big path only)
    const size_t BIG_NEED = 32788480ull + 134217728ull;   // 167,006,208

    prep_k<<<256, 256, 0, stream>>>(W1, W2, Wp1, Wp2);
    query_k<<<2048, 256, 0, stream>>>(xyz, rot, idx);
    featT_k<<<dim3(64, 8, 4), 256, 0, stream>>>(feat, featT);
    gxyz_k<<<1024, 256, 0, stream>>>(xyz, rot, idx, gxyz);

    if (ws_size >= BIG_NEED) {
        // pass 1: GEMM1 + fragment-layout y1 spill + stats1
        fused_k<0, 1><<<NBLK, 256, 0, stream>>>(featT, gxyz, idx, Wp1, Wp2, ab1, psum, psq, ymax, ymin, y1f);
        reduce_k<<<256, 256, 0, stream>>>(psum, psq, gamma1, beta1, ab1);
        // pass 2: reload y1 frags -> norm/relu -> GEMM2 + stats2 + max/min
        fused2_k<<<NBLK, 256, 0, stream>>>(y1f, Wp2, ab1, psum, psq, ymax, ymin);
        reduce_k<<<256, 256, 0, stream>>>(psum, psq, gamma2, beta2, ab2);
    } else {
        // fallback (round-2 proven path): recompute GEMM1 in pass 2
        fused_k<0, 0><<<NBLK, 256, 0, stream>>>(featT, gxyz, idx, Wp1, Wp2, ab1, psum, psq, ymax, ymin, nullptr);
        reduce_k<<<256, 256, 0, stream>>>(psum, psq, gamma1, beta1, ab1);
        fused_k<1, 0><<<NBLK, 256, 0, stream>>>(featT, gxyz, idx, Wp1, Wp2, ab1, psum, psq, ymax, ymin, nullptr);
        reduce_k<<<256, 256, 0, stream>>>(psum, psq, gamma2, beta2, ab2);
    }
    final_k<<<dim3(64, 8, 4), 256, 0, stream>>>(ymax, ymin, ab2, out);
}